// Round 1
// baseline (204.329 us; speedup 1.0000x reference)
//
#include <hip/hip_runtime.h>
#include <math.h>

#define BQ 8
#define MQ 64
#define REGMAX 16
#define KTOP 10
#define EPSQ 1e-7f

// ---------------- decode: DFL softmax expected value + pred atan ----------------
__global__ __launch_bounds__(256) void decode_kernel(
    const float* __restrict__ boxes, float* __restrict__ pb,
    float* __restrict__ patan, int N) {
  int i = blockIdx.x * 256 + threadIdx.x;
  int total = BQ * N;
  if (i >= total) return;
  int b = i / N;
  int n = i - b * N;
  const float* base = boxes + (size_t)b * (4 * REGMAX) * N + n;
  float out[4];
#pragma unroll
  for (int k = 0; k < 4; ++k) {
    float x[REGMAX];
#pragma unroll
    for (int r = 0; r < REGMAX; ++r)
      x[r] = base[(size_t)(k * REGMAX + r) * N];
    float mx = x[0];
#pragma unroll
    for (int r = 1; r < REGMAX; ++r) mx = fmaxf(mx, x[r]);
    float s = 0.f, ws = 0.f;
#pragma unroll
    for (int r = 0; r < REGMAX; ++r) {
      float e = __expf(x[r] - mx);
      s += e;
      ws += (float)r * e;
    }
    out[k] = ws / s;
  }
  ((float4*)pb)[i] = make_float4(out[0], out[1], out[2], out[3]);
  float w1 = out[2] - out[0], h1 = out[3] - out[1];
  patan[i] = atanf(w1 / (h1 + EPSQ));
}

// ---------------- topk: one block per (b,m), stream N anchors ----------------
__global__ __launch_bounds__(256) void topk_kernel(
    const float4* __restrict__ pb, const float* __restrict__ patan,
    const float* __restrict__ targets, unsigned int* __restrict__ iou_bits,
    int N) {
  const int b = blockIdx.x >> 6;   // / MQ
  const int m = blockIdx.x & 63;   // % MQ
  const int tid = threadIdx.x;

  const float4 t = ((const float4*)targets)[b * MQ + m];
  const float x21 = t.x, y21 = t.y, x22 = t.z, y22 = t.w;
  const float w2 = x22 - x21, h2 = y22 - y21;
  const float atan_t = atanf(w2 / (h2 + EPSQ));
  const float area2 = w2 * h2;
  const float sumx2 = x21 + x22, sumy2 = y21 + y22;
  const float CPI = 4.0f / (float)(M_PI * M_PI);

  float tv[KTOP];
  int ti[KTOP];
#pragma unroll
  for (int j = 0; j < KTOP; ++j) { tv[j] = 0.f; ti[j] = 0; }
  float tmin = 0.f;
  int minpos = 0;

  const float4* pbb = pb + (size_t)b * N;
  const float* pab = patan + (size_t)b * N;

  for (int n = tid; n < N; n += 256) {
    float4 p = pbb[n];
    float pa = pab[n];
    float x11 = p.x, y11 = p.y, x12 = p.z, y12 = p.w;
    float w1 = x12 - x11, h1 = y12 - y11;
    float iw = fmaxf(fminf(x12, x22) - fmaxf(x11, x21), 0.f);
    float ih = fmaxf(fminf(y12, y22) - fmaxf(y11, y21), 0.f);
    float inter = iw * ih;
    float uni = w1 * h1 + area2 - inter + EPSQ;
    float iou = inter / uni;
    float cw = fmaxf(x12, x22) - fminf(x11, x21);
    float ch = fmaxf(y12, y22) - fminf(y11, y21);
    float c2 = cw * cw + ch * ch + EPSQ;
    float dx = sumx2 - x11 - x12;
    float dy = sumy2 - y11 - y12;
    float rho2 = (dx * dx + dy * dy) * 0.25f;
    float da = atan_t - pa;
    float v = CPI * da * da;
    float alpha = v / (v - iou + 1.f + EPSQ);
    float ciou = iou - rho2 / c2 - alpha * v;

    if (ciou > tmin) {
#pragma unroll
      for (int j = 0; j < KTOP; ++j)
        if (j == minpos) { tv[j] = ciou; ti[j] = n; }
      tmin = tv[0]; minpos = 0;
#pragma unroll
      for (int j = 1; j < KTOP; ++j)
        if (tv[j] < tmin) { tmin = tv[j]; minpos = j; }
    }
  }

  // block-level top-10 via 10 rounds of argmax; winners scatter directly
  __shared__ unsigned long long sred[256];
  unsigned int* row = iou_bits + (size_t)b * N;
  for (int round = 0; round < KTOP; ++round) {
    float lmax = tv[0];
    int lpos = 0;
#pragma unroll
    for (int j = 1; j < KTOP; ++j)
      if (tv[j] > lmax) { lmax = tv[j]; lpos = j; }
    unsigned long long key =
        ((unsigned long long)__float_as_uint(lmax) << 32) | (unsigned int)tid;
    sred[tid] = key;
    __syncthreads();
    for (int s = 128; s > 0; s >>= 1) {
      if (tid < s) {
        unsigned long long a = sred[tid], c = sred[tid + s];
        sred[tid] = (a >= c) ? a : c;
      }
      __syncthreads();
    }
    unsigned long long win = sred[0];
    __syncthreads();
    float wv = __uint_as_float((unsigned int)(win >> 32));
    if (wv <= 0.f) break;  // uniform across block
    int wtid = (int)(win & 0xffffffffu);
    if (tid == wtid) {
      atomicMax(&row[ti[lpos]], __float_as_uint(lmax));
#pragma unroll
      for (int j = 0; j < KTOP; ++j)
        if (j == lpos) tv[j] = 0.f;
    }
    __syncthreads();
  }
}

// ---------------- per-batch reductions ----------------
__global__ __launch_bounds__(256) void reduce_kernel(
    const float* __restrict__ scores, const unsigned int* __restrict__ iou_bits,
    float* __restrict__ acc, int N, int bpb) {
  int b = blockIdx.x / bpb;
  int cb = blockIdx.x % bpb;
  int tid = threadIdx.x;
  float s_box = 0.f, s_cnt = 0.f, s_bce = 0.f;
  const unsigned int* row = iou_bits + (size_t)b * N;
  const float* srow = scores + (size_t)b * N;
  for (int n = cb * 256 + tid; n < N; n += bpb * 256) {
    float t = __uint_as_float(row[n]);
    float sc = srow[n];
    s_bce += fmaxf(sc, 0.f) - sc * t + log1pf(__expf(-fabsf(sc)));
    if (t > 0.f) { s_box += 1.f - t; s_cnt += 1.f; }
  }
  __shared__ float r0[256], r1[256], r2[256];
  r0[tid] = s_box; r1[tid] = s_cnt; r2[tid] = s_bce;
  __syncthreads();
  for (int s = 128; s > 0; s >>= 1) {
    if (tid < s) {
      r0[tid] += r0[tid + s];
      r1[tid] += r1[tid + s];
      r2[tid] += r2[tid + s];
    }
    __syncthreads();
  }
  if (tid == 0) {
    atomicAdd(&acc[b * 4 + 0], r0[0]);
    atomicAdd(&acc[b * 4 + 1], r1[0]);
    atomicAdd(&acc[b * 4 + 2], r2[0]);
  }
}

__global__ void finalize_kernel(const float* __restrict__ acc,
                                float* __restrict__ out, int N) {
  if (threadIdx.x == 0 && blockIdx.x == 0) {
    float box_loss = 0.f, obj_loss = 0.f;
    for (int b = 0; b < BQ; ++b) {
      float sbox = acc[b * 4 + 0];
      float npos = acc[b * 4 + 1];
      float sbce = acc[b * 4 + 2];
      box_loss += (npos > 0.f) ? sbox / fmaxf(npos, 1.f) : 0.f;
      obj_loss += sbce / (float)N;
    }
    out[0] = (7.5f * box_loss + 1.0f * obj_loss) / (float)BQ;
    out[1] = box_loss;
    out[2] = obj_loss;
  }
}

extern "C" void kernel_launch(void* const* d_in, const int* in_sizes, int n_in,
                              void* d_out, int out_size, void* d_ws, size_t ws_size,
                              hipStream_t stream) {
  const float* boxes = (const float*)d_in[0];
  const float* scores = (const float*)d_in[1];
  const float* targets = (const float*)d_in[2];
  float* out = (float*)d_out;
  const int N = in_sizes[1] / BQ;  // scores is [B, N]

  char* ws = (char*)d_ws;
  size_t pb_bytes = (size_t)BQ * N * 4 * sizeof(float);
  size_t patan_bytes = (size_t)BQ * N * sizeof(float);
  size_t iou_bytes = (size_t)BQ * N * sizeof(unsigned int);
  float* pb = (float*)ws;
  float* patan = (float*)(ws + pb_bytes);
  unsigned int* iou_bits = (unsigned int*)(ws + pb_bytes + patan_bytes);
  float* acc = (float*)(ws + pb_bytes + patan_bytes + iou_bytes);

  hipMemsetAsync(iou_bits, 0, iou_bytes, stream);
  hipMemsetAsync(acc, 0, (size_t)BQ * 4 * sizeof(float), stream);

  int total = BQ * N;
  decode_kernel<<<(total + 255) / 256, 256, 0, stream>>>(boxes, pb, patan, N);
  topk_kernel<<<BQ * MQ, 256, 0, stream>>>((const float4*)pb, patan, targets,
                                           iou_bits, N);
  const int bpb = 64;
  reduce_kernel<<<BQ * bpb, 256, 0, stream>>>(scores, iou_bits, acc, N, bpb);
  finalize_kernel<<<1, 64, 0, stream>>>(acc, out, N);
}

// Round 2
// 167.960 us; speedup vs baseline: 1.2165x; 1.2165x over previous
//
#include <hip/hip_runtime.h>
#include <math.h>

#define BQ 8
#define MQ 64
#define REGMAX 16
#define KTOP 10
#define CH 4
#define EPSQ 1e-7f

__device__ __forceinline__ float frcp(float x) { return __builtin_amdgcn_rcpf(x); }

// ---------------- decode: DFL softmax EV + pred atan + zero-init of iou/acc ----------------
__global__ __launch_bounds__(256) void decode_kernel(
    const float* __restrict__ boxes, float* __restrict__ pb,
    float* __restrict__ patan, unsigned int* __restrict__ iou_bits,
    float* __restrict__ acc, int N) {
  int i = blockIdx.x * 256 + threadIdx.x;
  if (blockIdx.x == 0 && threadIdx.x < BQ * 4) acc[threadIdx.x] = 0.f;
  int total = BQ * N;
  if (i >= total) return;
  iou_bits[i] = 0u;
  int b = i / N;
  int n = i - b * N;
  const float* base = boxes + (size_t)b * (4 * REGMAX) * N + n;
  float out[4];
#pragma unroll
  for (int k = 0; k < 4; ++k) {
    float x[REGMAX];
#pragma unroll
    for (int r = 0; r < REGMAX; ++r)
      x[r] = base[(size_t)(k * REGMAX + r) * N];
    float mx = x[0];
#pragma unroll
    for (int r = 1; r < REGMAX; ++r) mx = fmaxf(mx, x[r]);
    float s = 0.f, ws = 0.f;
#pragma unroll
    for (int r = 0; r < REGMAX; ++r) {
      float e = __expf(x[r] - mx);
      s += e;
      ws += (float)r * e;
    }
    out[k] = ws * frcp(s);
  }
  ((float4*)pb)[i] = make_float4(out[0], out[1], out[2], out[3]);
  float w1 = out[2] - out[0], h1 = out[3] - out[1];
  patan[i] = atanf(w1 * frcp(h1 + EPSQ));
}

// ---------------- topk phase 1: (b,m,chunk) blocks, chunk-local exact top-10 ----------------
__global__ __launch_bounds__(256) void topk1_kernel(
    const float4* __restrict__ pb, const float* __restrict__ patan,
    const float* __restrict__ targets, float* __restrict__ cand_v,
    int* __restrict__ cand_i, int N) {
  const int blk = blockIdx.x;        // BQ*MQ*CH
  const int chunk = blk & (CH - 1);
  const int bm = blk >> 2;           // 0..511
  const int b = bm >> 6;
  const int m = bm & 63;
  const int tid = threadIdx.x;

  const float4 t = ((const float4*)targets)[b * MQ + m];
  const float x21 = t.x, y21 = t.y, x22 = t.z, y22 = t.w;
  const float w2 = x22 - x21, h2 = y22 - y21;
  const float atan_t = atanf(w2 * frcp(h2 + EPSQ));
  const float area2 = w2 * h2;
  const float sumx2 = x21 + x22, sumy2 = y21 + y22;
  const float CPI = 4.0f / (float)(M_PI * M_PI);

  float tv[KTOP];
  int ti[KTOP];
#pragma unroll
  for (int j = 0; j < KTOP; ++j) { tv[j] = 0.f; ti[j] = 0; }
  float tmin = 0.f;  // only ciou > 0 ever enters the heap -> all tv >= 0
  int minpos = 0;

  const int chunkN = (N + CH - 1) / CH;
  const int n0 = chunk * chunkN;
  const int n1 = min(N, n0 + chunkN);

  const float4* pbb = pb + (size_t)b * N;
  const float* pab = patan + (size_t)b * N;

  for (int n = n0 + tid; n < n1; n += 256) {
    float4 p = pbb[n];
    float pa = pab[n];
    float x11 = p.x, y11 = p.y, x12 = p.z, y12 = p.w;
    float w1 = x12 - x11, h1 = y12 - y11;
    float iw = fmaxf(fminf(x12, x22) - fmaxf(x11, x21), 0.f);
    float ih = fmaxf(fminf(y12, y22) - fmaxf(y11, y21), 0.f);
    float inter = iw * ih;
    float uni = w1 * h1 + area2 - inter + EPSQ;
    float iou = inter * frcp(uni);
    float cw = fmaxf(x12, x22) - fminf(x11, x21);
    float ch = fmaxf(y12, y22) - fminf(y11, y21);
    float c2 = cw * cw + ch * ch + EPSQ;
    float dx = sumx2 - x11 - x12;
    float dy = sumy2 - y11 - y12;
    float rho2 = (dx * dx + dy * dy) * 0.25f;
    float da = atan_t - pa;
    float v = CPI * da * da;
    float alpha = v * frcp(v - iou + 1.f + EPSQ);
    float ciou = iou - rho2 * frcp(c2) - alpha * v;

    if (ciou > tmin) {
#pragma unroll
      for (int j = 0; j < KTOP; ++j)
        if (j == minpos) { tv[j] = ciou; ti[j] = n; }
      tmin = tv[0]; minpos = 0;
#pragma unroll
      for (int j = 1; j < KTOP; ++j)
        if (tv[j] < tmin) { tmin = tv[j]; minpos = j; }
    }
  }

  // block top-10: per-thread running max + 10 rounds of shuffle argmax
  float lmax = tv[0];
  int lpos = 0;
#pragma unroll
  for (int j = 1; j < KTOP; ++j)
    if (tv[j] > lmax) { lmax = tv[j]; lpos = j; }

  __shared__ unsigned long long swred[4];
  const int out_base = bm * (CH * KTOP) + chunk * KTOP;
  for (int round = 0; round < KTOP; ++round) {
    unsigned long long key =
        ((unsigned long long)__float_as_uint(lmax) << 32) | (unsigned int)tid;
#pragma unroll
    for (int d = 1; d < 64; d <<= 1) {
      unsigned long long o = __shfl_xor(key, d, 64);
      if (o > key) key = o;
    }
    if ((tid & 63) == 0) swred[tid >> 6] = key;
    __syncthreads();
    unsigned long long win =
        max(max(swred[0], swred[1]), max(swred[2], swred[3]));
    __syncthreads();
    int wtid = (int)(win & 0xffffffffu);
    if (tid == wtid) {
      cand_v[out_base + round] = lmax;
      cand_i[out_base + round] = ti[lpos];
#pragma unroll
      for (int j = 0; j < KTOP; ++j)
        if (j == lpos) tv[j] = 0.f;
      lmax = tv[0]; lpos = 0;
#pragma unroll
      for (int j = 1; j < KTOP; ++j)
        if (tv[j] > lmax) { lmax = tv[j]; lpos = j; }
    }
  }
}

// ---------------- topk phase 2: rank 40 candidates per (b,m), scatter ----------------
__global__ __launch_bounds__(64) void topk2_kernel(
    const float* __restrict__ cand_v, const int* __restrict__ cand_i,
    unsigned int* __restrict__ iou_bits, int N) {
  const int bm = blockIdx.x;  // 0..511
  const int b = bm >> 6;
  const int tid = threadIdx.x;
  const int NC = CH * KTOP;  // 40
  __shared__ float sv[NC];
  __shared__ int si[NC];
  if (tid < NC) {
    sv[tid] = cand_v[bm * NC + tid];
    si[tid] = cand_i[bm * NC + tid];
  }
  __syncthreads();
  if (tid < NC) {
    float v = sv[tid];
    if (v > 0.f) {
      int rank = 0;
#pragma unroll
      for (int i = 0; i < NC; ++i)
        rank += (sv[i] > v) || (sv[i] == v && i < tid);
      if (rank < KTOP) {
        atomicMax(&iou_bits[(size_t)b * N + si[tid]], __float_as_uint(v));
      }
    }
  }
}

// ---------------- per-batch reductions ----------------
__global__ __launch_bounds__(256) void reduce_kernel(
    const float* __restrict__ scores, const unsigned int* __restrict__ iou_bits,
    float* __restrict__ acc, int N, int bpb) {
  int b = blockIdx.x / bpb;
  int cb = blockIdx.x % bpb;
  int tid = threadIdx.x;
  float s_box = 0.f, s_cnt = 0.f, s_bce = 0.f;
  const unsigned int* row = iou_bits + (size_t)b * N;
  const float* srow = scores + (size_t)b * N;
  for (int n = cb * 256 + tid; n < N; n += bpb * 256) {
    float t = __uint_as_float(row[n]);
    float sc = srow[n];
    s_bce += fmaxf(sc, 0.f) - sc * t + log1pf(__expf(-fabsf(sc)));
    if (t > 0.f) { s_box += 1.f - t; s_cnt += 1.f; }
  }
  __shared__ float r0[256], r1[256], r2[256];
  r0[tid] = s_box; r1[tid] = s_cnt; r2[tid] = s_bce;
  __syncthreads();
  for (int s = 128; s > 0; s >>= 1) {
    if (tid < s) {
      r0[tid] += r0[tid + s];
      r1[tid] += r1[tid + s];
      r2[tid] += r2[tid + s];
    }
    __syncthreads();
  }
  if (tid == 0) {
    atomicAdd(&acc[b * 4 + 0], r0[0]);
    atomicAdd(&acc[b * 4 + 1], r1[0]);
    atomicAdd(&acc[b * 4 + 2], r2[0]);
  }
}

__global__ void finalize_kernel(const float* __restrict__ acc,
                                float* __restrict__ out, int N) {
  if (threadIdx.x == 0 && blockIdx.x == 0) {
    float box_loss = 0.f, obj_loss = 0.f;
    for (int b = 0; b < BQ; ++b) {
      float sbox = acc[b * 4 + 0];
      float npos = acc[b * 4 + 1];
      float sbce = acc[b * 4 + 2];
      box_loss += (npos > 0.f) ? sbox / fmaxf(npos, 1.f) : 0.f;
      obj_loss += sbce / (float)N;
    }
    out[0] = (7.5f * box_loss + 1.0f * obj_loss) / (float)BQ;
    out[1] = box_loss;
    out[2] = obj_loss;
  }
}

extern "C" void kernel_launch(void* const* d_in, const int* in_sizes, int n_in,
                              void* d_out, int out_size, void* d_ws, size_t ws_size,
                              hipStream_t stream) {
  const float* boxes = (const float*)d_in[0];
  const float* scores = (const float*)d_in[1];
  const float* targets = (const float*)d_in[2];
  float* out = (float*)d_out;
  const int N = in_sizes[1] / BQ;  // scores is [B, N]

  char* ws = (char*)d_ws;
  size_t pb_bytes = (size_t)BQ * N * 4 * sizeof(float);
  size_t patan_bytes = (size_t)BQ * N * sizeof(float);
  size_t iou_bytes = (size_t)BQ * N * sizeof(unsigned int);
  size_t acc_bytes = (size_t)BQ * 4 * sizeof(float);
  size_t cand_bytes = (size_t)BQ * MQ * CH * KTOP * sizeof(float);

  float* pb = (float*)ws;                      ws += pb_bytes;
  float* patan = (float*)ws;                   ws += patan_bytes;
  unsigned int* iou_bits = (unsigned int*)ws;  ws += iou_bytes;
  float* acc = (float*)ws;                     ws += acc_bytes;
  float* cand_v = (float*)ws;                  ws += cand_bytes;
  int* cand_i = (int*)ws;

  int total = BQ * N;
  decode_kernel<<<(total + 255) / 256, 256, 0, stream>>>(boxes, pb, patan,
                                                         iou_bits, acc, N);
  topk1_kernel<<<BQ * MQ * CH, 256, 0, stream>>>((const float4*)pb, patan,
                                                 targets, cand_v, cand_i, N);
  topk2_kernel<<<BQ * MQ, 64, 0, stream>>>(cand_v, cand_i, iou_bits, N);
  const int bpb = 64;
  reduce_kernel<<<BQ * bpb, 256, 0, stream>>>(scores, iou_bits, acc, N, bpb);
  finalize_kernel<<<1, 64, 0, stream>>>(acc, out, N);
}